// Round 1
// baseline (42194.586 us; speedup 1.0000x reference)
//
#include <hip/hip_runtime.h>
#include <math.h>

#define BATCH 64
#define NN 512
#define MS 511                       // minor size (root row/col removed)
#define LDM 512                      // row stride
#define MSTRIDE ((size_t)MS*LDM)     // 261632 floats per batch (ws M / KT buffer)
#define OSTRIDE ((size_t)NN*NN)      // 262144 floats per batch (d_out-hosted Y/X buffer)

// ---- input layout conversion (mask may be bool bytes / int32 / int64; target int32 / int64) ----
__global__ void k_convert(const void* __restrict__ mask_raw,
                          const void* __restrict__ tgt_raw,
                          int* __restrict__ cmask, int* __restrict__ ctgt) {
  int b = blockIdx.x;
  const unsigned char* mb = (const unsigned char*)mask_raw;
  const int* mw = (const int*)mask_raw;
  const int* tw = (const int*)tgt_raw;
  // mask layout detect: bool-bytes => bytes 1..3 are mask[1..3]=1 (lens>=384). int32/int64 => 0.
  bool m_bytes = (mb[1] | mb[2] | mb[3]) != 0;
  bool m_64 = false;
  if (!m_bytes) {
    int acc = 0;
    for (int j = 1; j < 32; j += 2) acc |= mw[j];
    m_64 = (acc == 0);               // int64: odd words are high halves = 0
  }
  int tacc = 0;
  for (int j = 1; j < 32; j += 2) tacc |= tw[j];
  bool t_64 = (tacc == 0);           // targets random in [0,512): some odd word nonzero if int32
  for (int i = threadIdx.x; i < NN; i += blockDim.x) {
    size_t idx = (size_t)b * NN + i;
    int mv;
    if (m_bytes) mv = mb[idx] != 0;
    else if (m_64) mv = mw[2 * idx] != 0;
    else mv = mw[idx] != 0;
    cmask[idx] = mv;
    ctgt[idx] = t_64 ? tw[2 * idx] : tw[idx];
  }
}

// ---- build Laplacian minor M[b] (rows/cols 1..511 of L), padding rows = identity ----
__global__ void k_build_M(const float* __restrict__ scores,
                          const int* __restrict__ mask,
                          float* __restrict__ M) {
  int b = blockIdx.y;
  int ip = blockIdx.x;               // minor row, original i = ip+1
  int i = ip + 1;
  const int* mrow = mask + (size_t)b * NN;
  float* Mrow = M + (size_t)b * MSTRIDE + (size_t)ip * LDM;
  if (!mrow[i]) {
    for (int jp = threadIdx.x; jp < MS; jp += blockDim.x)
      Mrow[jp] = (jp == ip) ? 1.0f : 0.0f;
    return;
  }
  const float* srow = scores + ((size_t)b * NN + i) * NN;
  double part = 0.0;                 // d_i in f64 (matches reference f64 sum of f32 exps)
  for (int j = threadIdx.x; j < NN; j += blockDim.x) {
    bool mj = (j == 0) || (mrow[j] != 0);
    if (mj) part += (double)expf(srow[j]);
  }
  __shared__ double red[256];
  red[threadIdx.x] = part;
  __syncthreads();
  for (int s = 128; s > 0; s >>= 1) {
    if (threadIdx.x < s) red[threadIdx.x] += red[threadIdx.x + s];
    __syncthreads();
  }
  float d = (float)red[0];
  for (int jp = threadIdx.x; jp < MS; jp += blockDim.x) {
    int j = jp + 1;
    float a = (mrow[j] != 0) ? expf(srow[j]) : 0.0f;
    float v = -a;
    if (jp == ip) v += d;            // M_ii = d_i - A_ii
    Mrow[jp] = v;
  }
}

// ---- LU (no pivoting; M is strictly row-diagonally-dominant) fused with forward solve Y=L^-1 ----
__global__ __launch_bounds__(1024) void k_lu_fwd(float* __restrict__ M,
                                                 float* __restrict__ Y,
                                                 double* __restrict__ ld) {
  int b = blockIdx.x;
  float* Mb = M + (size_t)b * MSTRIDE;
  float* Yb = Y + (size_t)b * OSTRIDE;
  int tid = threadIdx.x, lane = tid & 63, wid = tid >> 6;
  const int NW = 16;
  __shared__ float pivU[MS];
  __shared__ float pivY[MS];
  __shared__ float spiv;
  // Y = I
  for (int i = wid; i < MS; i += NW) {
    float* Yi = Yb + (size_t)i * LDM;
    for (int j = lane; j < MS; j += 64) Yi[j] = (i == j) ? 1.0f : 0.0f;
  }
  double acc = 0.0;
  for (int k = 0; k < MS; ++k) {
    __syncthreads();                 // prev updates + init visible
    float* Mk = Mb + (size_t)k * LDM;
    float* Yk = Yb + (size_t)k * LDM;
    int ncols = MS - 1 - k;
    for (int c = tid; c < ncols; c += 1024) pivU[c] = Mk[k + 1 + c];
    for (int c = tid; c <= k; c += 1024) pivY[c] = Yk[c];
    if (tid == 0) spiv = Mk[k];
    __syncthreads();
    float piv = spiv;
    if (tid == 0) acc += log(fabs((double)piv));
    float rp = 1.0f / piv;
    for (int r = wid; r < ncols; r += NW) {     // rows k+1 .. MS-1
      int i = k + 1 + r;
      float* Mi = Mb + (size_t)i * LDM;
      float* Yi = Yb + (size_t)i * LDM;
      float l = Mi[k] * rp;
      for (int c = lane; c < ncols; c += 64) Mi[k + 1 + c] -= l * pivU[c];
      for (int c = lane; c <= k; c += 64) Yi[c] -= l * pivY[c];
    }
  }
  if (tid == 0) ld[b] = acc;
}

// ---- back substitution: X = U^-1 Y, in place in Y ----
__global__ __launch_bounds__(1024) void k_back(const float* __restrict__ M,
                                               float* __restrict__ Y) {
  int b = blockIdx.x;
  const float* Mb = M + (size_t)b * MSTRIDE;
  float* Yb = Y + (size_t)b * OSTRIDE;
  int tid = threadIdx.x, lane = tid & 63, wid = tid >> 6;
  __shared__ float xk[MS];
  for (int k = MS - 1; k >= 0; --k) {
    __syncthreads();
    float rp = 1.0f / Mb[(size_t)k * LDM + k];
    float* Yk = Yb + (size_t)k * LDM;
    for (int c = tid; c < MS; c += 1024) {
      float x = Yk[c] * rp;
      Yk[c] = x;
      xk[c] = x;
    }
    __syncthreads();
    for (int r = wid; r < k; r += 16) {         // rows 0 .. k-1
      float u = Mb[(size_t)r * LDM + k];
      float* Yi = Yb + (size_t)r * LDM;
      for (int c = lane; c < MS; c += 64) Yi[c] -= u * xk[c];
    }
  }
}

// ---- transpose X (in d_out region) -> KT (in ws, reusing M buffer) ----
__global__ void k_transpose(const float* __restrict__ X, float* __restrict__ T) {
  __shared__ float tile[32][33];
  int b = blockIdx.z;
  const float* Xb = X + (size_t)b * OSTRIDE;
  float* Tb = T + (size_t)b * MSTRIDE;
  int i0 = blockIdx.x * 32, j0 = blockIdx.y * 32;
  int tx = threadIdx.x, ty = threadIdx.y;       // (32,8)
  for (int rr = 0; rr < 4; ++rr) {
    int i = i0 + ty + rr * 8, j = j0 + tx;
    if (i < MS && j < MS) tile[ty + rr * 8][tx] = Xb[(size_t)i * LDM + j];
  }
  __syncthreads();
  for (int rr = 0; rr < 4; ++rr) {
    int j = j0 + ty + rr * 8, i = i0 + tx;
    if (j < MS && i < MS) Tb[(size_t)j * LDM + i] = tile[tx][ty + rr * 8];
  }
}

// ---- marginals: out[b,i,k] = A_ik * (K[i-1,i-1] - (k>=1) K[k-1,i-1]) ----
__global__ void k_marginals(const float* __restrict__ scores,
                            const int* __restrict__ mask,
                            const float* __restrict__ T,
                            float* __restrict__ out1) {
  int b = blockIdx.y;
  int i = blockIdx.x;                // dependent index 0..511
  float* orow = out1 + ((size_t)b * NN + i) * NN;
  const int* mrow = mask + (size_t)b * NN;
  bool mi = (i >= 1) && (mrow[i] != 0);
  if (!mi) {
    for (int k = threadIdx.x; k < NN; k += blockDim.x) orow[k] = 0.0f;
    return;
  }
  const float* srow = scores + ((size_t)b * NN + i) * NN;
  const float* Trow = T + (size_t)b * MSTRIDE + (size_t)(i - 1) * LDM; // KT row i-1: KT[i-1][c]=K[c][i-1]
  float kd = Trow[i - 1];
  for (int k = threadIdx.x; k < NN; k += blockDim.x) {
    bool mk = (k == 0) || (mrow[k] != 0);
    float v = 0.0f;
    if (mk) {
      float a = expf(srow[k]);
      float sub = (k >= 1) ? Trow[k - 1] : 0.0f;
      v = a * (kd - sub);
    }
    orow[k] = v;
  }
}

// ---- gold score + mask count per batch ----
__global__ void k_gold(const float* __restrict__ scores,
                       const int* __restrict__ mask,
                       const int* __restrict__ target,
                       double* __restrict__ goldb, int* __restrict__ cntb) {
  int b = blockIdx.x;
  const int* mrow = mask + (size_t)b * NN;
  const int* trow = target + (size_t)b * NN;
  double g = 0.0;
  int c = 0;
  for (int i = threadIdx.x; i < NN; i += blockDim.x) {
    if (mrow[i] != 0) {
      g += (double)scores[((size_t)b * NN + i) * NN + trow[i]];
      c++;
    }
  }
  __shared__ double gs[256];
  __shared__ int cs[256];
  gs[threadIdx.x] = g;
  cs[threadIdx.x] = c;
  __syncthreads();
  for (int s = 128; s > 0; s >>= 1) {
    if (threadIdx.x < s) {
      gs[threadIdx.x] += gs[threadIdx.x + s];
      cs[threadIdx.x] += cs[threadIdx.x + s];
    }
    __syncthreads();
  }
  if (threadIdx.x == 0) { goldb[b] = gs[0]; cntb[b] = cs[0]; }
}

__global__ void k_final(const double* __restrict__ ld,
                        const double* __restrict__ goldb,
                        const int* __restrict__ cntb, float* __restrict__ out) {
  double lz = 0.0, g = 0.0;
  long long cnt = 0;
  for (int b = 0; b < BATCH; ++b) { lz += ld[b]; g += goldb[b]; cnt += cntb[b]; }
  out[0] = (float)((lz - g) / (double)cnt);
}

extern "C" void kernel_launch(void* const* d_in, const int* in_sizes, int n_in,
                              void* d_out, int out_size, void* d_ws, size_t ws_size,
                              hipStream_t stream) {
  const float* scores = (const float*)d_in[0];
  const void* mask_raw = d_in[1];
  const void* tgt_raw = d_in[2];
  float* out = (float*)d_out;
  float* out1 = out + 1;

  float* Mbuf = (float*)d_ws;                                  // 66,977,792 B
  size_t moff = (MSTRIDE * BATCH * sizeof(float) + 255) & ~(size_t)255;
  double* ld = (double*)((char*)d_ws + moff);                  // 64 doubles
  double* goldb = ld + BATCH;                                  // 64 doubles
  int* cntb = (int*)(goldb + BATCH);                           // 64 ints
  int* cmask = cntb + BATCH;                                   // 32768 ints
  int* ctgt = cmask + BATCH * NN;                              // 32768 ints

  k_convert<<<BATCH, 256, 0, stream>>>(mask_raw, tgt_raw, cmask, ctgt);
  k_build_M<<<dim3(MS, BATCH), 256, 0, stream>>>(scores, cmask, Mbuf);
  k_lu_fwd<<<BATCH, 1024, 0, stream>>>(Mbuf, out1, ld);
  k_back<<<BATCH, 1024, 0, stream>>>(Mbuf, out1);
  k_transpose<<<dim3(16, 16, BATCH), dim3(32, 8), 0, stream>>>(out1, Mbuf);
  k_marginals<<<dim3(NN, BATCH), 256, 0, stream>>>(scores, cmask, Mbuf, out1);
  k_gold<<<BATCH, 256, 0, stream>>>(scores, cmask, ctgt, goldb, cntb);
  k_final<<<1, 1, 0, stream>>>(ld, goldb, cntb, out);
}

// Round 2
// 7282.669 us; speedup vs baseline: 5.7938x; 5.7938x over previous
//
#include <hip/hip_runtime.h>
#include <math.h>

#define BATCH 64
#define NN 512
#define MS 511                       // minor size (root row/col removed)
#define LDM 512                      // row stride
#define MSTRIDE ((size_t)MS*LDM)     // floats per batch in ws M buffer
#define NB 32                        // LU block size

// ---- input layout conversion (mask may be bool bytes / int32 / int64; target int32 / int64) ----
__global__ void k_convert(const void* __restrict__ mask_raw,
                          const void* __restrict__ tgt_raw,
                          int* __restrict__ cmask, int* __restrict__ ctgt) {
  int b = blockIdx.x;
  const unsigned char* mb = (const unsigned char*)mask_raw;
  const int* mw = (const int*)mask_raw;
  const int* tw = (const int*)tgt_raw;
  bool m_bytes = (mb[1] | mb[2] | mb[3]) != 0;
  bool m_64 = false;
  if (!m_bytes) {
    int acc = 0;
    for (int j = 1; j < 32; j += 2) acc |= mw[j];
    m_64 = (acc == 0);
  }
  int tacc = 0;
  for (int j = 1; j < 32; j += 2) tacc |= tw[j];
  bool t_64 = (tacc == 0);
  for (int i = threadIdx.x; i < NN; i += blockDim.x) {
    size_t idx = (size_t)b * NN + i;
    int mv;
    if (m_bytes) mv = mb[idx] != 0;
    else if (m_64) mv = mw[2 * idx] != 0;
    else mv = mw[idx] != 0;
    cmask[idx] = mv;
    ctgt[idx] = t_64 ? tw[2 * idx] : tw[idx];
  }
}

// ---- build Laplacian minor M[b] (rows/cols 1..511 of L), padding rows = identity ----
__global__ void k_build_M(const float* __restrict__ scores,
                          const int* __restrict__ mask,
                          float* __restrict__ M) {
  int b = blockIdx.y;
  int ip = blockIdx.x;               // minor row, original i = ip+1
  int i = ip + 1;
  const int* mrow = mask + (size_t)b * NN;
  float* Mrow = M + (size_t)b * MSTRIDE + (size_t)ip * LDM;
  if (!mrow[i]) {
    for (int jp = threadIdx.x; jp < MS; jp += blockDim.x)
      Mrow[jp] = (jp == ip) ? 1.0f : 0.0f;
    return;
  }
  const float* srow = scores + ((size_t)b * NN + i) * NN;
  double part = 0.0;
  for (int j = threadIdx.x; j < NN; j += blockDim.x) {
    bool mj = (j == 0) || (mrow[j] != 0);
    if (mj) part += (double)expf(srow[j]);
  }
  __shared__ double red[256];
  red[threadIdx.x] = part;
  __syncthreads();
  for (int s = 128; s > 0; s >>= 1) {
    if (threadIdx.x < s) red[threadIdx.x] += red[threadIdx.x + s];
    __syncthreads();
  }
  float d = (float)red[0];
  for (int jp = threadIdx.x; jp < MS; jp += blockDim.x) {
    int j = jp + 1;
    float a = (mrow[j] != 0) ? expf(srow[j]) : 0.0f;
    float v = -a;
    if (jp == ip) v += d;
    Mrow[jp] = v;
  }
}

// ---- blocked LU (no pivoting; M strictly row-diagonally-dominant), factor only ----
__global__ __launch_bounds__(1024) void k_lu(float* __restrict__ M,
                                             double* __restrict__ ld) {
  int b = blockIdx.x;
  float* Mb = M + (size_t)b * MSTRIDE;
  int tid = threadIdx.x;
  __shared__ __align__(16) float P[MS * 33];      // panel, padded stride 33 (67.4 KB)
  __shared__ __align__(16) float Us[NB * 260];    // staged U12 col-tile (33.3 KB)
  __shared__ double lgred[NB];
  double acc = 0.0;

  for (int kb = 0; kb < MS; kb += NB) {
    int rem = MS - kb;
    int nb = rem < NB ? rem : NB;
    __syncthreads();                 // prev GEMM done before re-staging P / reading Mb
    // stage panel: P[r][c] = M[kb+r][kb+c]
    for (int idx = tid; idx < rem * NB; idx += 1024) {
      int r = idx >> 5, c = idx & 31;
      P[r * 33 + c] = (c < nb) ? Mb[(size_t)(kb + r) * LDM + (kb + c)] : 0.0f;
    }
    __syncthreads();
    // factor panel in LDS: one thread per row
    for (int j = 0; j < nb; ++j) {
      float piv = P[j * 33 + j];
      int r = tid;
      if (r > j && r < rem) {
        float l = P[r * 33 + j] / piv;
        P[r * 33 + j] = l;
        for (int c = j + 1; c < nb; ++c)
          P[r * 33 + c] -= l * P[j * 33 + c];
      }
      __syncthreads();
    }
    // logdet partials + write panel back
    if (tid < nb) lgred[tid] = log(fabs((double)P[tid * 33 + tid]));
    for (int idx = tid; idx < rem * NB; idx += 1024) {
      int r = idx >> 5, c = idx & 31;
      if (c < nb) Mb[(size_t)(kb + r) * LDM + (kb + c)] = P[r * 33 + c];
    }
    __syncthreads();
    if (tid == 0) {
      for (int j = 0; j < nb; ++j) acc += lgred[j];
    }

    int rem2 = rem - NB;
    if (rem2 > 0) {
      int c0g = kb + NB;
      // U12 = inv(L11) * A12, one column per thread, registers
      for (int c2 = tid; c2 < rem2; c2 += 1024) {
        int cg = c0g + c2;
        float u[NB];
#pragma unroll
        for (int i = 0; i < NB; ++i) {
          float v = Mb[(size_t)(kb + i) * LDM + cg];
#pragma unroll
          for (int k2 = 0; k2 < NB; ++k2)
            if (k2 < i) v -= P[i * 33 + k2] * u[k2];
          u[i] = v;
        }
#pragma unroll
        for (int i = 0; i < NB; ++i)
          Mb[(size_t)(kb + i) * LDM + cg] = u[i];
      }
      // trailing GEMM: A22 -= L21 * U12 (L21 from P, U12 staged in Us)
      int ty = tid >> 5, tx = tid & 31;
      for (int rt = 0; rt < rem2; rt += 128) {
        for (int ct = 0; ct < rem2; ct += 256) {
          __syncthreads();           // U12 writes visible / prev Us readers done
          for (int idx = tid; idx < NB * 256; idx += 1024) {
            int k2 = idx >> 8, c = idx & 255;
            int cg = c0g + ct + c;
            Us[k2 * 260 + c] = (cg < NN) ? Mb[(size_t)(kb + k2) * LDM + cg] : 0.0f;
          }
          __syncthreads();
          int cg0 = c0g + ct + tx * 8;
          if (cg0 < NN) {
            int pr0 = NB + rt + ty * 4;
            float ac[4][8];
            bool rv[4];
#pragma unroll
            for (int i = 0; i < 4; ++i) {
              rv[i] = (pr0 + i) < rem;
              if (rv[i]) {
                const float4* cp = (const float4*)&Mb[(size_t)(kb + pr0 + i) * LDM + cg0];
                float4 v0 = cp[0], v1 = cp[1];
                ac[i][0] = v0.x; ac[i][1] = v0.y; ac[i][2] = v0.z; ac[i][3] = v0.w;
                ac[i][4] = v1.x; ac[i][5] = v1.y; ac[i][6] = v1.z; ac[i][7] = v1.w;
              } else {
#pragma unroll
                for (int j2 = 0; j2 < 8; ++j2) ac[i][j2] = 0.0f;
              }
            }
#pragma unroll 8
            for (int k2 = 0; k2 < NB; ++k2) {
              float4 u0 = *(const float4*)&Us[k2 * 260 + tx * 8];
              float4 u1 = *(const float4*)&Us[k2 * 260 + tx * 8 + 4];
              float uu[8] = {u0.x, u0.y, u0.z, u0.w, u1.x, u1.y, u1.z, u1.w};
#pragma unroll
              for (int i = 0; i < 4; ++i) {
                int pri = rv[i] ? (pr0 + i) : 0;
                float a = rv[i] ? P[pri * 33 + k2] : 0.0f;
#pragma unroll
                for (int j2 = 0; j2 < 8; ++j2)
                  ac[i][j2] = fmaf(-a, uu[j2], ac[i][j2]);
              }
            }
#pragma unroll
            for (int i = 0; i < 4; ++i) {
              if (rv[i]) {
                float4 v0 = {ac[i][0], ac[i][1], ac[i][2], ac[i][3]};
                float4 v1 = {ac[i][4], ac[i][5], ac[i][6], ac[i][7]};
                float4* cp = (float4*)&Mb[(size_t)(kb + pr0 + i) * LDM + cg0];
                cp[0] = v0; cp[1] = v1;
              }
            }
          }
        }
      }
    }
  }
  if (tid == 0) ld[b] = acc;
}

// ---- per-(batch, 16-col block) inverse columns + fused marginals ----
// 16 lanes per column, all within one wave -> NO barriers in the solve loops.
__global__ __launch_bounds__(256) void k_solve_marg(const float* __restrict__ M,
                                                    const float* __restrict__ scores,
                                                    const int* __restrict__ mask,
                                                    float* __restrict__ out1) {
  int b = blockIdx.x;                // batch on blockIdx.x => same-batch WGs share XCD/L2
  int cb = blockIdx.y;               // column block 0..31
  const float* Mb = M + (size_t)b * MSTRIDE;
  int tid = threadIdx.x;
  int cl = tid >> 4;                 // 0..15 column-local
  int sub = tid & 15;                // 0..15 reduction lane
  int c0 = cb * 16;
  int cg = c0 + cl;                  // global column of K this group solves (511 = junk, harmless)
  __shared__ float X[16 * 520];      // X[col][row], padded stride 520 (2-way banks)
  for (int idx = tid; idx < 16 * 520; idx += 256) X[idx] = 0.0f;
  __syncthreads();
  float* Xc = X + cl * 520;

  // forward: L y = e_cg  (unit lower L; y_k = 0 for k < c0 by column sparsity)
  for (int k = c0; k < MS; ++k) {
    const float* Lk = Mb + (size_t)k * LDM;
    float partial = 0.0f;
    for (int j = c0 + sub; j < k; j += 16)
      partial += Lk[j] * Xc[j];
    partial += __shfl_xor(partial, 1, 16);
    partial += __shfl_xor(partial, 2, 16);
    partial += __shfl_xor(partial, 4, 16);
    partial += __shfl_xor(partial, 8, 16);
    float y = ((k == cg) ? 1.0f : 0.0f) - partial;
    if (sub == 0) Xc[k] = y;
  }
  // backward: U x = y, in place
  for (int k = MS - 1; k >= 0; --k) {
    const float* Uk = Mb + (size_t)k * LDM;
    float partial = 0.0f;
    for (int j = k + 1 + sub; j < MS; j += 16)
      partial += Uk[j] * Xc[j];
    partial += __shfl_xor(partial, 1, 16);
    partial += __shfl_xor(partial, 2, 16);
    partial += __shfl_xor(partial, 4, 16);
    partial += __shfl_xor(partial, 8, 16);
    float x = (Xc[k] - partial) / Uk[k];
    if (sub == 0) Xc[k] = x;
  }

  // marginals for output row i = cg+1 directly from column cg of K:
  // out[b,i,k] = A_ik * (K[i-1,i-1] - (k>=1 ? K[k-1,i-1] : 0))
  int i = cg + 1;
  const int* mrow = mask + (size_t)b * NN;
  if (i < NN) {
    float* orow = out1 + ((size_t)b * NN + i) * NN;
    if (mrow[i] == 0) {
      for (int k = sub; k < NN; k += 16) orow[k] = 0.0f;
    } else {
      const float* srow = scores + ((size_t)b * NN + i) * NN;
      float kd = Xc[cg];
      for (int k = sub; k < NN; k += 16) {
        bool mk = (k == 0) || (mrow[k] != 0);
        float v = 0.0f;
        if (mk) {
          float s2 = (k >= 1) ? Xc[k - 1] : 0.0f;
          v = expf(srow[k]) * (kd - s2);
        }
        orow[k] = v;
      }
    }
  }
  if (cb == 0 && cl == 0) {          // root row i = 0 is all zeros
    float* orow = out1 + (size_t)b * NN * NN;
    for (int k = sub; k < NN; k += 16) orow[k] = 0.0f;
  }
}

// ---- gold score + mask count per batch ----
__global__ void k_gold(const float* __restrict__ scores,
                       const int* __restrict__ mask,
                       const int* __restrict__ target,
                       double* __restrict__ goldb, int* __restrict__ cntb) {
  int b = blockIdx.x;
  const int* mrow = mask + (size_t)b * NN;
  const int* trow = target + (size_t)b * NN;
  double g = 0.0;
  int c = 0;
  for (int i = threadIdx.x; i < NN; i += blockDim.x) {
    if (mrow[i] != 0) {
      g += (double)scores[((size_t)b * NN + i) * NN + trow[i]];
      c++;
    }
  }
  __shared__ double gs[256];
  __shared__ int cs[256];
  gs[threadIdx.x] = g;
  cs[threadIdx.x] = c;
  __syncthreads();
  for (int s = 128; s > 0; s >>= 1) {
    if (threadIdx.x < s) {
      gs[threadIdx.x] += gs[threadIdx.x + s];
      cs[threadIdx.x] += cs[threadIdx.x + s];
    }
    __syncthreads();
  }
  if (threadIdx.x == 0) { goldb[b] = gs[0]; cntb[b] = cs[0]; }
}

__global__ void k_final(const double* __restrict__ ld,
                        const double* __restrict__ goldb,
                        const int* __restrict__ cntb, float* __restrict__ out) {
  double lz = 0.0, g = 0.0;
  long long cnt = 0;
  for (int b = 0; b < BATCH; ++b) { lz += ld[b]; g += goldb[b]; cnt += cntb[b]; }
  out[0] = (float)((lz - g) / (double)cnt);
}

extern "C" void kernel_launch(void* const* d_in, const int* in_sizes, int n_in,
                              void* d_out, int out_size, void* d_ws, size_t ws_size,
                              hipStream_t stream) {
  const float* scores = (const float*)d_in[0];
  const void* mask_raw = d_in[1];
  const void* tgt_raw = d_in[2];
  float* out = (float*)d_out;
  float* out1 = out + 1;

  float* Mbuf = (float*)d_ws;
  size_t moff = (MSTRIDE * BATCH * sizeof(float) + 255) & ~(size_t)255;
  double* ld = (double*)((char*)d_ws + moff);
  double* goldb = ld + BATCH;
  int* cntb = (int*)(goldb + BATCH);
  int* cmask = cntb + BATCH;
  int* ctgt = cmask + BATCH * NN;

  k_convert<<<BATCH, 256, 0, stream>>>(mask_raw, tgt_raw, cmask, ctgt);
  k_build_M<<<dim3(MS, BATCH), 256, 0, stream>>>(scores, cmask, Mbuf);
  k_lu<<<BATCH, 1024, 0, stream>>>(Mbuf, ld);
  k_solve_marg<<<dim3(BATCH, 32), 256, 0, stream>>>(Mbuf, scores, cmask, out1);
  k_gold<<<BATCH, 256, 0, stream>>>(scores, cmask, ctgt, goldb, cntb);
  k_final<<<1, 1, 0, stream>>>(ld, goldb, cntb, out);
}

// Round 3
// 2749.418 us; speedup vs baseline: 15.3467x; 2.6488x over previous
//
#include <hip/hip_runtime.h>
#include <math.h>

#define BATCH 64
#define NN 512
#define MS 511                       // minor size (root row/col removed)
#define LDM 512                      // row stride
#define MSTRIDE ((size_t)MS*LDM)     // floats per batch in ws M buffer
#define PB 64                        // LU panel width
#define PS 66                        // panel LDS stride

// ---- input layout conversion (mask may be bool bytes / int32 / int64; target int32 / int64) ----
__global__ void k_convert(const void* __restrict__ mask_raw,
                          const void* __restrict__ tgt_raw,
                          int* __restrict__ cmask, int* __restrict__ ctgt) {
  int b = blockIdx.x;
  const unsigned char* mb = (const unsigned char*)mask_raw;
  const int* mw = (const int*)mask_raw;
  const int* tw = (const int*)tgt_raw;
  bool m_bytes = (mb[1] | mb[2] | mb[3]) != 0;
  bool m_64 = false;
  if (!m_bytes) {
    int acc = 0;
    for (int j = 1; j < 32; j += 2) acc |= mw[j];
    m_64 = (acc == 0);
  }
  int tacc = 0;
  for (int j = 1; j < 32; j += 2) tacc |= tw[j];
  bool t_64 = (tacc == 0);
  for (int i = threadIdx.x; i < NN; i += blockDim.x) {
    size_t idx = (size_t)b * NN + i;
    int mv;
    if (m_bytes) mv = mb[idx] != 0;
    else if (m_64) mv = mw[2 * idx] != 0;
    else mv = mw[idx] != 0;
    cmask[idx] = mv;
    ctgt[idx] = t_64 ? tw[2 * idx] : tw[idx];
  }
}

// ---- build Laplacian minor M[b] ----
__global__ void k_build_M(const float* __restrict__ scores,
                          const int* __restrict__ mask,
                          float* __restrict__ M) {
  int b = blockIdx.y;
  int ip = blockIdx.x;
  int i = ip + 1;
  const int* mrow = mask + (size_t)b * NN;
  float* Mrow = M + (size_t)b * MSTRIDE + (size_t)ip * LDM;
  if (!mrow[i]) {
    for (int jp = threadIdx.x; jp < MS; jp += blockDim.x)
      Mrow[jp] = (jp == ip) ? 1.0f : 0.0f;
    return;
  }
  const float* srow = scores + ((size_t)b * NN + i) * NN;
  double part = 0.0;
  for (int j = threadIdx.x; j < NN; j += blockDim.x) {
    bool mj = (j == 0) || (mrow[j] != 0);
    if (mj) part += (double)expf(srow[j]);
  }
  __shared__ double red[256];
  red[threadIdx.x] = part;
  __syncthreads();
  for (int s = 128; s > 0; s >>= 1) {
    if (threadIdx.x < s) red[threadIdx.x] += red[threadIdx.x + s];
    __syncthreads();
  }
  float d = (float)red[0];
  for (int jp = threadIdx.x; jp < MS; jp += blockDim.x) {
    int j = jp + 1;
    float a = (mrow[j] != 0) ? expf(srow[j]) : 0.0f;
    float v = -a;
    if (jp == ip) v += d;
    Mrow[jp] = v;
  }
}

// ---- LU panel: factor 64 cols (rows kb..510) in LDS + U12 TRSM for trailing cols ----
__global__ __launch_bounds__(512) void k_panel(float* __restrict__ M, int kb,
                                               double* __restrict__ ld2) {
  int b = blockIdx.x;
  float* Mb = M + (size_t)b * MSTRIDE;
  int tid = threadIdx.x;
  int rem = MS - kb;                     // real rows
  int re = rem < PB ? PB : rem;          // padded row count (last panel)
  int nbr = rem < PB ? rem : PB;         // real cols
  __shared__ float P[511 * PS];          // 134.9 KB
  __shared__ double lgred[PB];

  // stage (padded identity beyond real rows/cols)
  for (int idx = tid; idx < re * PB; idx += 512) {
    int r = idx >> 6, c = idx & 63;
    float v;
    if (kb + r < MS && kb + c < MS) v = Mb[(size_t)(kb + r) * LDM + (kb + c)];
    else v = (r == c) ? 1.0f : 0.0f;
    P[r * PS + c] = v;
  }
  __syncthreads();

  // ---- factor cols 0..31 ----
  for (int j = 0; j < 32; ++j) {
    float piv = P[j * PS + j];
    int r = j + 1 + tid;
    if (r < re) {
      float l = P[r * PS + j] / piv;
      P[r * PS + j] = l;
      for (int c = j + 1; c < 32; ++c)
        P[r * PS + c] -= l * P[j * PS + c];
    }
    __syncthreads();
  }
  // ---- inner TRSM: cols 32..63 rows 0..31 ----
  if (tid < 32) {
    int c = 32 + tid;
    float u[32];
#pragma unroll
    for (int i = 0; i < 32; ++i) {
      float v = P[i * PS + c];
#pragma unroll
      for (int k = 0; k < 32; ++k)
        if (k < i) v -= P[i * PS + k] * u[k];
      u[i] = v;
      P[i * PS + c] = v;
    }
  }
  __syncthreads();
  // ---- inner GEMM: rows 32..re-1, cols 32..63 ----
  {
    int tx = tid & 31, ty = tid >> 5;
    int c = 32 + tx;
    for (int r = 32 + ty; r < re; r += 16) {
      float acc = P[r * PS + c];
#pragma unroll
      for (int k = 0; k < 32; ++k)
        acc -= P[r * PS + k] * P[k * PS + c];
      P[r * PS + c] = acc;
    }
  }
  __syncthreads();
  // ---- factor cols 32..63 ----
  for (int j = 32; j < 64; ++j) {
    float piv = P[j * PS + j];
    int r = j + 1 + tid;
    if (r < re) {
      float l = P[r * PS + j] / piv;
      P[r * PS + j] = l;
      for (int c = j + 1; c < 64; ++c)
        P[r * PS + c] -= l * P[j * PS + c];
    }
    __syncthreads();
  }

  // logdet partials (fake diag entries are exactly 1 -> log 0)
  if (tid < PB) lgred[tid] = log(fabs((double)P[tid * PS + tid]));
  // write back panel (real rows/cols only)
  for (int idx = tid; idx < rem * PB; idx += 512) {
    int r = idx >> 6, c = idx & 63;
    if (c < nbr) Mb[(size_t)(kb + r) * LDM + (kb + c)] = P[r * PS + c];
  }
  __syncthreads();
  if (tid == 0) {
    double a = 0.0;
    for (int j = 0; j < PB; ++j) a += lgred[j];
    ld2[(kb / PB) * BATCH + b] = a;
  }

  // ---- U12 for trailing cols: solve L11 * u = A12 per column ----
  int rem2 = rem - PB;
  if (rem2 > 0) {
    for (int c2 = tid; c2 < rem2; c2 += 512) {
      int cg = kb + PB + c2;
      float u[PB];
#pragma unroll
      for (int i = 0; i < PB; ++i) u[i] = Mb[(size_t)(kb + i) * LDM + cg];
#pragma unroll
      for (int i = 1; i < PB; ++i) {
        float v = u[i];
#pragma unroll
        for (int k = 0; k < PB; ++k)
          if (k < i) v -= P[i * PS + k] * u[k];
        u[i] = v;
      }
#pragma unroll
      for (int i = 0; i < PB; ++i) Mb[(size_t)(kb + i) * LDM + cg] = u[i];
    }
  }
}

// ---- trailing rank-64 update: C -= L21 * U12, 64x64 tiles ----
__global__ __launch_bounds__(256) void k_update(float* __restrict__ M, int kb) {
  int b = blockIdx.z;
  float* Mb = M + (size_t)b * MSTRIDE;
  int row0 = kb + PB + blockIdx.x * 64;
  int col0 = kb + PB + blockIdx.y * 64;
  __shared__ float As[64 * 68];
  __shared__ float Bs[64 * 68];
  int tid = threadIdx.x;
  for (int idx = tid; idx < 64 * 16; idx += 256) {
    int r = idx >> 4, k4 = (idx & 15) * 4;
    int gr = row0 + r;
    float4 av;
    if (gr < MS) av = *(const float4*)&Mb[(size_t)gr * LDM + kb + k4];
    else av = make_float4(0.f, 0.f, 0.f, 0.f);
    *(float4*)&As[r * 68 + k4] = av;
    float4 bv = *(const float4*)&Mb[(size_t)(kb + r) * LDM + col0 + k4];
    *(float4*)&Bs[r * 68 + k4] = bv;
  }
  __syncthreads();
  int tx = tid & 15, ty = tid >> 4;
  float acc[4][4];
  bool rv[4];
#pragma unroll
  for (int i = 0; i < 4; ++i) {
    int gr = row0 + ty + 16 * i;
    rv[i] = gr < MS;
    if (rv[i]) {
      float4 v = *(const float4*)&Mb[(size_t)gr * LDM + col0 + tx * 4];
      acc[i][0] = v.x; acc[i][1] = v.y; acc[i][2] = v.z; acc[i][3] = v.w;
    } else {
      acc[i][0] = acc[i][1] = acc[i][2] = acc[i][3] = 0.0f;
    }
  }
#pragma unroll 8
  for (int k = 0; k < 64; ++k) {
    float4 bv = *(const float4*)&Bs[k * 68 + tx * 4];
    float bq[4] = {bv.x, bv.y, bv.z, bv.w};
    float aq[4] = {As[ty * 68 + k], As[(ty + 16) * 68 + k],
                   As[(ty + 32) * 68 + k], As[(ty + 48) * 68 + k]};
#pragma unroll
    for (int i = 0; i < 4; ++i)
#pragma unroll
      for (int j = 0; j < 4; ++j)
        acc[i][j] = fmaf(-aq[i], bq[j], acc[i][j]);
  }
#pragma unroll
  for (int i = 0; i < 4; ++i) {
    if (rv[i]) {
      int gr = row0 + ty + 16 * i;
      float4 v = {acc[i][0], acc[i][1], acc[i][2], acc[i][3]};
      *(float4*)&Mb[(size_t)gr * LDM + col0 + tx * 4] = v;
    }
  }
}

// ---- blocked TRSM inverse columns (32 per WG, LDS-resident) + fused marginals ----
__global__ __launch_bounds__(256) void k_solve(const float* __restrict__ M,
                                               const float* __restrict__ scores,
                                               const int* __restrict__ mask,
                                               float* __restrict__ out1) {
  int b = blockIdx.x;                  // batch-major grid => same-batch WGs share XCD
  int cb = blockIdx.y;                 // 0..15 column block
  const float* Mb = M + (size_t)b * MSTRIDE;
  int tid = threadIdx.x;
  int c0 = cb * 32;
  __shared__ float Y[512 * 33];        // Y[row][col], row 511 = pad (67.6 KB)
  __shared__ float D[32 * 33];

  for (int idx = tid; idx < 512 * 33; idx += 256) Y[idx] = 0.0f;
  __syncthreads();
  if (tid < 32) {
    int cg = c0 + tid;
    if (cg < MS) Y[cg * 33 + tid] = 1.0f;
  }
  __syncthreads();

  int tx = tid & 31, ty = tid >> 5;    // 8 row groups for GEMM

  // ======== forward: L Y = I (start at diagonal block; rows < c0 are 0) ========
  for (int jb = c0; jb < MS; jb += 32) {
    for (int idx = tid; idx < 32 * 32; idx += 256) {
      int r = idx >> 5, c = idx & 31;
      int gr = jb + r, gc = jb + c;
      D[r * 33 + c] = (gr < MS && gc < MS) ? Mb[(size_t)gr * LDM + gc]
                                           : ((r == c) ? 1.0f : 0.0f);
    }
    __syncthreads();
    if (tid < 32) {                    // lane-serial 32x32 unit-lower TRSM
      float y[32];
#pragma unroll
      for (int jj = 0; jj < 32; ++jj) y[jj] = Y[(jb + jj) * 33 + tid];
#pragma unroll
      for (int j = 0; j < 32; ++j) {
        float yj = y[j];
#pragma unroll
        for (int jj = 0; jj < 32; ++jj)
          if (jj > j) y[jj] -= D[jj * 33 + j] * yj;
      }
#pragma unroll
      for (int jj = 0; jj < 32; ++jj) Y[(jb + jj) * 33 + tid] = y[jj];
    }
    __syncthreads();
    // GEMM: rows jb+32..510: Y[r] -= L[r][jb..jb+31] * Yblock
    for (int r = jb + 32 + ty; r < MS; r += 8) {
      float acc = Y[r * 33 + tx];
      const float4* L4 = (const float4*)(Mb + (size_t)r * LDM + jb);
      float lv[32];
#pragma unroll
      for (int q = 0; q < 8; ++q) {
        float4 v = L4[q];
        lv[4 * q] = v.x; lv[4 * q + 1] = v.y; lv[4 * q + 2] = v.z; lv[4 * q + 3] = v.w;
      }
#pragma unroll
      for (int k = 0; k < 32; ++k)
        acc -= lv[k] * Y[(jb + k) * 33 + tx];
      Y[r * 33 + tx] = acc;
    }
    __syncthreads();
  }

  // ======== backward: U X = Y ========
  for (int jb = 480; jb >= 0; jb -= 32) {
    for (int idx = tid; idx < 32 * 32; idx += 256) {
      int r = idx >> 5, c = idx & 31;
      int gr = jb + r, gc = jb + c;
      D[r * 33 + c] = (gr < MS && gc < MS) ? Mb[(size_t)gr * LDM + gc]
                                           : ((r == c) ? 1.0f : 0.0f);
    }
    __syncthreads();
    if (tid < 32) {                    // lane-serial 32x32 upper TRSM
      float y[32];
#pragma unroll
      for (int jj = 0; jj < 32; ++jj) y[jj] = Y[(jb + jj) * 33 + tid];
#pragma unroll
      for (int j = 31; j >= 0; --j) {
        float xv = y[j] / D[j * 33 + j];
        y[j] = xv;
#pragma unroll
        for (int jj = 0; jj < 32; ++jj)
          if (jj < j) y[jj] -= D[jj * 33 + j] * xv;
      }
#pragma unroll
      for (int jj = 0; jj < 32; ++jj) Y[(jb + jj) * 33 + tid] = y[jj];
    }
    __syncthreads();
    // GEMM: rows 0..jb-1: Y[r] -= U[r][jb..jb+31] * Yblock
    for (int r = ty; r < jb; r += 8) {
      float acc = Y[r * 33 + tx];
      const float4* U4 = (const float4*)(Mb + (size_t)r * LDM + jb);
      float lv[32];
#pragma unroll
      for (int q = 0; q < 8; ++q) {
        float4 v = U4[q];
        lv[4 * q] = v.x; lv[4 * q + 1] = v.y; lv[4 * q + 2] = v.z; lv[4 * q + 3] = v.w;
      }
#pragma unroll
      for (int k = 0; k < 32; ++k)
        acc -= lv[k] * Y[(jb + k) * 33 + tx];
      Y[r * 33 + tx] = acc;
    }
    __syncthreads();
  }

  // ======== fused marginals: out row i = cg+1 from K column cg ========
  const int* mrow = mask + (size_t)b * NN;
  const float* sb = scores + (size_t)b * NN * NN;
  float* ob = out1 + (size_t)b * NN * NN;
  for (int c = 0; c < 32; ++c) {
    int i = c0 + c + 1;
    if (i >= NN) break;
    float* orow = ob + (size_t)i * NN;
    if (mrow[i] == 0) {
      for (int k = tid; k < NN; k += 256) orow[k] = 0.0f;
    } else {
      const float* srow = sb + (size_t)i * NN;
      float kd = Y[(i - 1) * 33 + c];
      for (int k = tid; k < NN; k += 256) {
        bool mk = (k == 0) || (mrow[k] != 0);
        float v = 0.0f;
        if (mk) {
          float s2 = (k >= 1) ? Y[(k - 1) * 33 + c] : 0.0f;
          v = expf(srow[k]) * (kd - s2);
        }
        orow[k] = v;
      }
    }
  }
  if (cb == 0) {
    for (int k = tid; k < NN; k += 256) ob[k] = 0.0f;   // root row i=0
  }
}

// ---- gold score + mask count per batch ----
__global__ void k_gold(const float* __restrict__ scores,
                       const int* __restrict__ mask,
                       const int* __restrict__ target,
                       double* __restrict__ goldb, int* __restrict__ cntb) {
  int b = blockIdx.x;
  const int* mrow = mask + (size_t)b * NN;
  const int* trow = target + (size_t)b * NN;
  double g = 0.0;
  int c = 0;
  for (int i = threadIdx.x; i < NN; i += blockDim.x) {
    if (mrow[i] != 0) {
      g += (double)scores[((size_t)b * NN + i) * NN + trow[i]];
      c++;
    }
  }
  __shared__ double gs[256];
  __shared__ int cs[256];
  gs[threadIdx.x] = g;
  cs[threadIdx.x] = c;
  __syncthreads();
  for (int s = 128; s > 0; s >>= 1) {
    if (threadIdx.x < s) {
      gs[threadIdx.x] += gs[threadIdx.x + s];
      cs[threadIdx.x] += cs[threadIdx.x + s];
    }
    __syncthreads();
  }
  if (threadIdx.x == 0) { goldb[b] = gs[0]; cntb[b] = cs[0]; }
}

__global__ void k_final(const double* __restrict__ ld2,
                        const double* __restrict__ goldb,
                        const int* __restrict__ cntb, float* __restrict__ out) {
  double lz = 0.0, g = 0.0;
  long long cnt = 0;
  for (int s = 0; s < 8 * BATCH; ++s) lz += ld2[s];
  for (int b = 0; b < BATCH; ++b) { g += goldb[b]; cnt += cntb[b]; }
  out[0] = (float)((lz - g) / (double)cnt);
}

extern "C" void kernel_launch(void* const* d_in, const int* in_sizes, int n_in,
                              void* d_out, int out_size, void* d_ws, size_t ws_size,
                              hipStream_t stream) {
  const float* scores = (const float*)d_in[0];
  const void* mask_raw = d_in[1];
  const void* tgt_raw = d_in[2];
  float* out = (float*)d_out;
  float* out1 = out + 1;

  float* Mbuf = (float*)d_ws;
  size_t moff = (MSTRIDE * BATCH * sizeof(float) + 255) & ~(size_t)255;
  double* ld2 = (double*)((char*)d_ws + moff);         // 8*64 doubles
  double* goldb = ld2 + 8 * BATCH;
  int* cntb = (int*)(goldb + BATCH);
  int* cmask = cntb + BATCH;
  int* ctgt = cmask + BATCH * NN;

  k_convert<<<BATCH, 256, 0, stream>>>(mask_raw, tgt_raw, cmask, ctgt);
  k_build_M<<<dim3(MS, BATCH), 256, 0, stream>>>(scores, cmask, Mbuf);

  for (int kb = 0; kb < MS; kb += PB) {
    k_panel<<<BATCH, 512, 0, stream>>>(Mbuf, kb, ld2);
    int rem2 = MS - kb - PB;
    if (rem2 > 0) {
      int nt = (rem2 + 63) / 64;
      k_update<<<dim3(nt, nt, BATCH), 256, 0, stream>>>(Mbuf, kb);
    }
  }

  k_solve<<<dim3(BATCH, 16), 256, 0, stream>>>(Mbuf, scores, cmask, out1);
  k_gold<<<BATCH, 256, 0, stream>>>(scores, cmask, ctgt, goldb, cntb);
  k_final<<<1, 1, 0, stream>>>(ld2, goldb, cntb, out);
}

// Round 4
// 1933.686 us; speedup vs baseline: 21.8208x; 1.4219x over previous
//
#include <hip/hip_runtime.h>
#include <math.h>

#define BATCH 64
#define NN 512
#define MS 511                       // minor size (root row/col removed)
#define LDM 512                      // row stride
#define MSTRIDE ((size_t)MS*LDM)     // floats per batch in ws M buffer
#define PB 64                        // LU panel width

// Y LDS: stride 32, XOR swizzle to kill column-access bank conflicts
#define YS(r,c) (((r)<<5) + (((c)) ^ ((r)&31)))

// ---- input layout conversion (mask may be bool bytes / int32 / int64; target int32 / int64) ----
__global__ void k_convert(const void* __restrict__ mask_raw,
                          const void* __restrict__ tgt_raw,
                          int* __restrict__ cmask, int* __restrict__ ctgt) {
  int b = blockIdx.x;
  const unsigned char* mb = (const unsigned char*)mask_raw;
  const int* mw = (const int*)mask_raw;
  const int* tw = (const int*)tgt_raw;
  bool m_bytes = (mb[1] | mb[2] | mb[3]) != 0;
  bool m_64 = false;
  if (!m_bytes) {
    int acc = 0;
    for (int j = 1; j < 32; j += 2) acc |= mw[j];
    m_64 = (acc == 0);
  }
  int tacc = 0;
  for (int j = 1; j < 32; j += 2) tacc |= tw[j];
  bool t_64 = (tacc == 0);
  for (int i = threadIdx.x; i < NN; i += blockDim.x) {
    size_t idx = (size_t)b * NN + i;
    int mv;
    if (m_bytes) mv = mb[idx] != 0;
    else if (m_64) mv = mw[2 * idx] != 0;
    else mv = mw[idx] != 0;
    cmask[idx] = mv;
    ctgt[idx] = t_64 ? tw[2 * idx] : tw[idx];
  }
}

// ---- build Laplacian minor M[b], single pass over scores ----
__global__ void k_build_M(const float* __restrict__ scores,
                          const int* __restrict__ mask,
                          float* __restrict__ M) {
  int b = blockIdx.y;
  int ip = blockIdx.x;
  int i = ip + 1;
  const int* mrow = mask + (size_t)b * NN;
  float* Mrow = M + (size_t)b * MSTRIDE + (size_t)ip * LDM;
  int tid = threadIdx.x;
  if (!mrow[i]) {
    for (int jp = tid; jp < MS; jp += 256)
      Mrow[jp] = (jp == ip) ? 1.0f : 0.0f;
    return;
  }
  const float* srow = scores + ((size_t)b * NN + i) * NN;
  double part = 0.0;
  for (int j = tid; j < NN; j += 256) {
    bool mj = (j == 0) || (mrow[j] != 0);
    float e = mj ? expf(srow[j]) : 0.0f;
    part += (double)e;
    if (j >= 1) Mrow[j - 1] = -e;    // column jp = j-1
  }
  __shared__ double red[256];
  red[tid] = part;
  __syncthreads();
  for (int s = 128; s > 0; s >>= 1) {
    if (tid < s) red[tid] += red[tid + s];
    __syncthreads();
  }
  // diagonal fix by the thread that wrote Mrow[ip] (owns j == i)
  if (tid == (i & 255)) Mrow[ip] += (float)red[0];
}

// ---- factor 64x64 diagonal block + invert L11/U11 ----
__global__ __launch_bounds__(256) void k_panel64(float* __restrict__ M, int kb,
                                                 double* __restrict__ ld2,
                                                 float* __restrict__ invLg,
                                                 float* __restrict__ invUg) {
  int b = blockIdx.x;
  float* Mb = M + (size_t)b * MSTRIDE;
  int tid = threadIdx.x;
  __shared__ float A[64 * 65];
  __shared__ float XU[64 * 66];
  __shared__ float XL[64 * 66];
  __shared__ double lg[64];

  for (int idx = tid; idx < 64 * 64; idx += 256) {
    int r = idx >> 6, c = idx & 63;
    int gr = kb + r, gc = kb + c;
    A[r * 65 + c] = (gr < MS && gc < MS) ? Mb[(size_t)gr * LDM + gc]
                                         : ((r == c) ? 1.0f : 0.0f);
  }
  __syncthreads();

  int rr = tid >> 2, sub = tid & 3;   // 4 subs per row, same-wave adjacent
  // factor (no pivoting, diagonally dominant)
  for (int j = 0; j < 63; ++j) {
    if (rr > j) {
      float piv = A[j * 65 + j];
      float l = A[rr * 65 + j] / piv;  // all subs read BEFORE sub0 writes (program order)
      if (sub == 0) A[rr * 65 + j] = l;
      for (int c = j + 1 + sub; c < 64; c += 4)
        A[rr * 65 + c] -= l * A[j * 65 + c];
    }
    __syncthreads();
  }
  if (tid < 64) lg[tid] = log(fabs((double)A[tid * 65 + tid]));
  for (int idx = tid; idx < 64 * 64; idx += 256) {
    int r = idx >> 6, c = idx & 63;
    int gr = kb + r, gc = kb + c;
    if (gr < MS && gc < MS) Mb[(size_t)gr * LDM + gc] = A[r * 65 + c];
  }
  __syncthreads();
  if (tid == 0) {
    double a = 0.0;
    for (int j = 0; j < 64; ++j) a += lg[j];
    ld2[(kb >> 6) * BATCH + b] = a;
  }

  // invU column rr (upper, non-unit); 4 subs shfl-split the dot products.
  {
    int c = rr;
    if (sub == 0) XU[c * 66 + c] = 1.0f / A[c * 65 + c];
    for (int r2 = c - 1; r2 >= 0; --r2) {
      float s = 0.0f;
      for (int k = r2 + 1 + sub; k <= c; k += 4)
        s += A[r2 * 65 + k] * XU[c * 66 + k];
      s += __shfl_xor(s, 1, 4);
      s += __shfl_xor(s, 2, 4);
      if (sub == 0) XU[c * 66 + r2] = -s / A[r2 * 65 + r2];
    }
  }
  // invL column rr (unit lower)
  {
    int c = rr;
    if (sub == 0) XL[c * 66 + c] = 1.0f;
    for (int r2 = c + 1; r2 < 64; ++r2) {
      float s = 0.0f;
      for (int k = c + sub; k < r2; k += 4)
        s += A[r2 * 65 + k] * XL[c * 66 + k];
      s += __shfl_xor(s, 1, 4);
      s += __shfl_xor(s, 2, 4);
      if (sub == 0) XL[c * 66 + r2] = -s;
    }
  }
  __syncthreads();
  float* iLg = invLg + ((size_t)(kb >> 6) * BATCH + b) * 4096;
  float* iUg = invUg + ((size_t)(kb >> 6) * BATCH + b) * 4096;
  for (int idx = tid; idx < 4096; idx += 256) {
    int r = idx >> 6, c = idx & 63;
    iUg[idx] = (r <= c) ? XU[c * 66 + r] : 0.0f;   // row-major invU
    iLg[idx] = (r >= c) ? XL[c * 66 + r] : 0.0f;   // row-major invL
  }
}

// ---- TRSM-as-GEMM: side0: U12_t = invL11 * A12_t ; side1: L21_t = A21_t * invU11 ----
__global__ __launch_bounds__(256) void k_trsm(float* __restrict__ M, int kb,
                                              const float* __restrict__ invLg,
                                              const float* __restrict__ invUg) {
  int b = blockIdx.z;
  int t = blockIdx.x;
  int side = blockIdx.y;
  float* Mb = M + (size_t)b * MSTRIDE;
  const float* inv = (side == 0 ? invLg : invUg) + ((size_t)(kb >> 6) * BATCH + b) * 4096;
  __shared__ float Fs[64 * 65];
  __shared__ float As[64 * 65];
  int tid = threadIdx.x;
  int off = kb + 64 + t * 64;
  for (int idx = tid; idx < 4096; idx += 256)
    Fs[(idx >> 6) * 65 + (idx & 63)] = inv[idx];
  for (int idx = tid; idx < 4096; idx += 256) {
    int r = idx >> 6, c = idx & 63;
    int gr, gc;
    if (side == 0) { gr = kb + r; gc = off + c; }
    else           { gr = off + r; gc = kb + c; }
    As[r * 65 + c] = (gr < MS && gc < MS) ? Mb[(size_t)gr * LDM + gc] : 0.0f;
  }
  __syncthreads();
  int tx = tid & 15, ty = tid >> 4;
  float acc[4][4];
#pragma unroll
  for (int i = 0; i < 4; ++i)
#pragma unroll
    for (int j = 0; j < 4; ++j) acc[i][j] = 0.0f;
  if (side == 0) {
#pragma unroll 4
    for (int k = 0; k < 64; ++k) {
      float av[4], bv[4];
#pragma unroll
      for (int i = 0; i < 4; ++i) av[i] = Fs[(ty * 4 + i) * 65 + k];
#pragma unroll
      for (int j = 0; j < 4; ++j) bv[j] = As[k * 65 + tx * 4 + j];
#pragma unroll
      for (int i = 0; i < 4; ++i)
#pragma unroll
        for (int j = 0; j < 4; ++j) acc[i][j] = fmaf(av[i], bv[j], acc[i][j]);
    }
  } else {
#pragma unroll 4
    for (int k = 0; k < 64; ++k) {
      float av[4], bv[4];
#pragma unroll
      for (int i = 0; i < 4; ++i) av[i] = As[(ty * 4 + i) * 65 + k];
#pragma unroll
      for (int j = 0; j < 4; ++j) bv[j] = Fs[k * 65 + tx * 4 + j];
#pragma unroll
      for (int i = 0; i < 4; ++i)
#pragma unroll
        for (int j = 0; j < 4; ++j) acc[i][j] = fmaf(av[i], bv[j], acc[i][j]);
    }
  }
#pragma unroll
  for (int i = 0; i < 4; ++i) {
#pragma unroll
    for (int j = 0; j < 4; ++j) {
      int gr, gc;
      if (side == 0) { gr = kb + ty * 4 + i; gc = off + tx * 4 + j; }
      else           { gr = off + ty * 4 + i; gc = kb + tx * 4 + j; }
      if (gr < MS && gc < MS) Mb[(size_t)gr * LDM + gc] = acc[i][j];
    }
  }
}

// ---- trailing rank-64 update: C -= L21 * U12, 64x64 tiles ----
__global__ __launch_bounds__(256) void k_update(float* __restrict__ M, int kb) {
  int b = blockIdx.z;
  float* Mb = M + (size_t)b * MSTRIDE;
  int row0 = kb + PB + blockIdx.x * 64;
  int col0 = kb + PB + blockIdx.y * 64;
  __shared__ float As[64 * 68];
  __shared__ float Bs[64 * 68];
  int tid = threadIdx.x;
  for (int idx = tid; idx < 64 * 16; idx += 256) {
    int r = idx >> 4, k4 = (idx & 15) * 4;
    int gr = row0 + r;
    float4 av;
    if (gr < MS) av = *(const float4*)&Mb[(size_t)gr * LDM + kb + k4];
    else av = make_float4(0.f, 0.f, 0.f, 0.f);
    *(float4*)&As[r * 68 + k4] = av;
    float4 bv = *(const float4*)&Mb[(size_t)(kb + r) * LDM + col0 + k4];
    *(float4*)&Bs[r * 68 + k4] = bv;
  }
  __syncthreads();
  int tx = tid & 15, ty = tid >> 4;
  float acc[4][4];
  bool rv[4];
#pragma unroll
  for (int i = 0; i < 4; ++i) {
    int gr = row0 + ty + 16 * i;
    rv[i] = gr < MS;
    if (rv[i]) {
      float4 v = *(const float4*)&Mb[(size_t)gr * LDM + col0 + tx * 4];
      acc[i][0] = v.x; acc[i][1] = v.y; acc[i][2] = v.z; acc[i][3] = v.w;
    } else {
      acc[i][0] = acc[i][1] = acc[i][2] = acc[i][3] = 0.0f;
    }
  }
#pragma unroll 8
  for (int k = 0; k < 64; ++k) {
    float4 bv = *(const float4*)&Bs[k * 68 + tx * 4];
    float bq[4] = {bv.x, bv.y, bv.z, bv.w};
    float aq[4] = {As[ty * 68 + k], As[(ty + 16) * 68 + k],
                   As[(ty + 32) * 68 + k], As[(ty + 48) * 68 + k]};
#pragma unroll
    for (int i = 0; i < 4; ++i)
#pragma unroll
      for (int j = 0; j < 4; ++j)
        acc[i][j] = fmaf(-aq[i], bq[j], acc[i][j]);
  }
#pragma unroll
  for (int i = 0; i < 4; ++i) {
    if (rv[i]) {
      int gr = row0 + ty + 16 * i;
      float4 v = {acc[i][0], acc[i][1], acc[i][2], acc[i][3]};
      *(float4*)&Mb[(size_t)gr * LDM + col0 + tx * 4] = v;
    }
  }
}

// ---- blocked TRSM inverse columns (32/WG) with LDS-staged L/U tiles + fused marginals ----
__global__ __launch_bounds__(256) void k_solve(const float* __restrict__ M,
                                               const float* __restrict__ scores,
                                               const int* __restrict__ mask,
                                               float* __restrict__ out1) {
  int b = blockIdx.x;
  int cb = blockIdx.y;
  const float* Mb = M + (size_t)b * MSTRIDE;
  int tid = threadIdx.x;
  int c0 = cb * 32;
  __shared__ float Y[512 * 32];        // 64 KB, XOR-swizzled
  __shared__ float D[32 * 33];         // 4.2 KB
  __shared__ float Lt[64 * 33];        // 8.4 KB

  for (int idx = tid; idx < 512 * 32; idx += 256) Y[idx] = 0.0f;
  __syncthreads();
  if (tid < 32) {
    int cg = c0 + tid;
    if (cg < MS) Y[YS(cg, tid)] = 1.0f;
  }
  __syncthreads();

  int tx = tid & 7, ty = tid >> 3;     // 8 col-groups x 32 row-pairs

  // ======== forward: L Y = I ========
  for (int jb = c0; jb < MS; jb += 32) {
    for (int idx = tid; idx < 1024; idx += 256) {
      int r = idx >> 5, c = idx & 31;
      int gr = jb + r, gc = jb + c;
      D[r * 33 + c] = (gr < MS && gc < MS) ? Mb[(size_t)gr * LDM + gc]
                                           : ((r == c) ? 1.0f : 0.0f);
    }
    __syncthreads();
    if (tid < 32) {                    // lane-serial 32x32 unit-lower TRSM, col = tid
      float y[32];
#pragma unroll
      for (int jj = 0; jj < 32; ++jj) y[jj] = Y[YS(jb + jj, tid)];
#pragma unroll
      for (int j = 0; j < 32; ++j) {
        float yj = y[j];
#pragma unroll
        for (int jj = 0; jj < 32; ++jj)
          if (jj > j) y[jj] -= D[jj * 33 + j] * yj;
      }
#pragma unroll
      for (int jj = 0; jj < 32; ++jj) Y[YS(jb + jj, tid)] = y[jj];
    }
    __syncthreads();
    for (int R0 = jb + 32; R0 < MS; R0 += 64) {
      for (int idx = tid; idx < 2048; idx += 256) {
        int rr = idx >> 5, k = idx & 31;
        int gr = R0 + rr;
        Lt[rr * 33 + k] = (gr < MS) ? Mb[(size_t)gr * LDM + jb + k] : 0.0f;
      }
      __syncthreads();
      int r0 = R0 + ty * 2;
      float acc[2][4];
#pragma unroll
      for (int i = 0; i < 2; ++i) {
        bool v = (r0 + i) < MS;
#pragma unroll
        for (int j = 0; j < 4; ++j)
          acc[i][j] = v ? Y[YS(r0 + i, tx * 4 + j)] : 0.0f;
      }
#pragma unroll 4
      for (int k = 0; k < 32; ++k) {
        float b0 = Y[YS(jb + k, tx * 4 + 0)];
        float b1 = Y[YS(jb + k, tx * 4 + 1)];
        float b2 = Y[YS(jb + k, tx * 4 + 2)];
        float b3 = Y[YS(jb + k, tx * 4 + 3)];
        float a0 = Lt[(ty * 2) * 33 + k];
        float a1 = Lt[(ty * 2 + 1) * 33 + k];
        acc[0][0] = fmaf(-a0, b0, acc[0][0]); acc[0][1] = fmaf(-a0, b1, acc[0][1]);
        acc[0][2] = fmaf(-a0, b2, acc[0][2]); acc[0][3] = fmaf(-a0, b3, acc[0][3]);
        acc[1][0] = fmaf(-a1, b0, acc[1][0]); acc[1][1] = fmaf(-a1, b1, acc[1][1]);
        acc[1][2] = fmaf(-a1, b2, acc[1][2]); acc[1][3] = fmaf(-a1, b3, acc[1][3]);
      }
#pragma unroll
      for (int i = 0; i < 2; ++i) {
        if ((r0 + i) < MS)
#pragma unroll
          for (int j = 0; j < 4; ++j)
            Y[YS(r0 + i, tx * 4 + j)] = acc[i][j];
      }
      __syncthreads();
    }
  }

  // ======== backward: U X = Y ========
  for (int jb = 480; jb >= 0; jb -= 32) {
    for (int idx = tid; idx < 1024; idx += 256) {
      int r = idx >> 5, c = idx & 31;
      int gr = jb + r, gc = jb + c;
      D[r * 33 + c] = (gr < MS && gc < MS) ? Mb[(size_t)gr * LDM + gc]
                                           : ((r == c) ? 1.0f : 0.0f);
    }
    __syncthreads();
    if (tid < 32) {                    // lane-serial 32x32 upper TRSM
      float y[32];
#pragma unroll
      for (int jj = 0; jj < 32; ++jj) y[jj] = Y[YS(jb + jj, tid)];
#pragma unroll
      for (int j = 31; j >= 0; --j) {
        float xv = y[j] / D[j * 33 + j];
        y[j] = xv;
#pragma unroll
        for (int jj = 0; jj < 32; ++jj)
          if (jj < j) y[jj] -= D[jj * 33 + j] * xv;
      }
#pragma unroll
      for (int jj = 0; jj < 32; ++jj) Y[YS(jb + jj, tid)] = y[jj];
    }
    __syncthreads();
    for (int R0 = 0; R0 < jb; R0 += 64) {
      for (int idx = tid; idx < 2048; idx += 256) {
        int rr = idx >> 5, k = idx & 31;
        int gr = R0 + rr;
        Lt[rr * 33 + k] = (gr < jb) ? Mb[(size_t)gr * LDM + jb + k] : 0.0f;
      }
      __syncthreads();
      int r0 = R0 + ty * 2;
      float acc[2][4];
#pragma unroll
      for (int i = 0; i < 2; ++i) {
        bool v = (r0 + i) < jb;
#pragma unroll
        for (int j = 0; j < 4; ++j)
          acc[i][j] = v ? Y[YS(r0 + i, tx * 4 + j)] : 0.0f;
      }
#pragma unroll 4
      for (int k = 0; k < 32; ++k) {
        float b0 = Y[YS(jb + k, tx * 4 + 0)];
        float b1 = Y[YS(jb + k, tx * 4 + 1)];
        float b2 = Y[YS(jb + k, tx * 4 + 2)];
        float b3 = Y[YS(jb + k, tx * 4 + 3)];
        float a0 = Lt[(ty * 2) * 33 + k];
        float a1 = Lt[(ty * 2 + 1) * 33 + k];
        acc[0][0] = fmaf(-a0, b0, acc[0][0]); acc[0][1] = fmaf(-a0, b1, acc[0][1]);
        acc[0][2] = fmaf(-a0, b2, acc[0][2]); acc[0][3] = fmaf(-a0, b3, acc[0][3]);
        acc[1][0] = fmaf(-a1, b0, acc[1][0]); acc[1][1] = fmaf(-a1, b1, acc[1][1]);
        acc[1][2] = fmaf(-a1, b2, acc[1][2]); acc[1][3] = fmaf(-a1, b3, acc[1][3]);
      }
#pragma unroll
      for (int i = 0; i < 2; ++i) {
        if ((r0 + i) < jb)
#pragma unroll
          for (int j = 0; j < 4; ++j)
            Y[YS(r0 + i, tx * 4 + j)] = acc[i][j];
      }
      __syncthreads();
    }
  }

  // ======== fused marginals: out row i = cg+1 from K column cg ========
  const int* mrow = mask + (size_t)b * NN;
  const float* sb = scores + (size_t)b * NN * NN;
  float* ob = out1 + (size_t)b * NN * NN;
  for (int c = 0; c < 32; ++c) {
    int i = c0 + c + 1;
    if (i >= NN) break;
    float* orow = ob + (size_t)i * NN;
    if (mrow[i] == 0) {
      for (int k = tid; k < NN; k += 256) orow[k] = 0.0f;
    } else {
      const float* srow = sb + (size_t)i * NN;
      float kd = Y[YS(i - 1, c)];
      for (int k = tid; k < NN; k += 256) {
        bool mk = (k == 0) || (mrow[k] != 0);
        float v = 0.0f;
        if (mk) {
          float s2 = (k >= 1) ? Y[YS(k - 1, c)] : 0.0f;
          v = expf(srow[k]) * (kd - s2);
        }
        orow[k] = v;
      }
    }
  }
  if (cb == 0) {
    for (int k = tid; k < NN; k += 256) ob[k] = 0.0f;   // root row i=0
  }
}

// ---- gold score + mask count per batch ----
__global__ void k_gold(const float* __restrict__ scores,
                       const int* __restrict__ mask,
                       const int* __restrict__ target,
                       double* __restrict__ goldb, int* __restrict__ cntb) {
  int b = blockIdx.x;
  const int* mrow = mask + (size_t)b * NN;
  const int* trow = target + (size_t)b * NN;
  double g = 0.0;
  int c = 0;
  for (int i = threadIdx.x; i < NN; i += blockDim.x) {
    if (mrow[i] != 0) {
      g += (double)scores[((size_t)b * NN + i) * NN + trow[i]];
      c++;
    }
  }
  __shared__ double gs[256];
  __shared__ int cs[256];
  gs[threadIdx.x] = g;
  cs[threadIdx.x] = c;
  __syncthreads();
  for (int s = 128; s > 0; s >>= 1) {
    if (threadIdx.x < s) {
      gs[threadIdx.x] += gs[threadIdx.x + s];
      cs[threadIdx.x] += cs[threadIdx.x + s];
    }
    __syncthreads();
  }
  if (threadIdx.x == 0) { goldb[b] = gs[0]; cntb[b] = cs[0]; }
}

__global__ void k_final(const double* __restrict__ ld2,
                        const double* __restrict__ goldb,
                        const int* __restrict__ cntb, float* __restrict__ out) {
  double lz = 0.0, g = 0.0;
  long long cnt = 0;
  for (int s = 0; s < 8 * BATCH; ++s) lz += ld2[s];
  for (int b = 0; b < BATCH; ++b) { g += goldb[b]; cnt += cntb[b]; }
  out[0] = (float)((lz - g) / (double)cnt);
}

extern "C" void kernel_launch(void* const* d_in, const int* in_sizes, int n_in,
                              void* d_out, int out_size, void* d_ws, size_t ws_size,
                              hipStream_t stream) {
  const float* scores = (const float*)d_in[0];
  const void* mask_raw = d_in[1];
  const void* tgt_raw = d_in[2];
  float* out = (float*)d_out;
  float* out1 = out + 1;

  float* Mbuf = (float*)d_ws;
  size_t moff = (MSTRIDE * BATCH * sizeof(float) + 255) & ~(size_t)255;
  double* ld2 = (double*)((char*)d_ws + moff);         // 8*64 doubles
  double* goldb = ld2 + 8 * BATCH;
  int* cntb = (int*)(goldb + BATCH);
  int* cmask = cntb + BATCH;
  int* ctgt = cmask + BATCH * NN;

  // inv-block scratch: 2 x 8 x 64 x 4096 floats = 16.8 MB. Prefer ws; else
  // stash in d_out region (fully overwritten later by k_solve's marginals).
  size_t small_end = moff + 512 * 1024;
  size_t inv_need = small_end + (size_t)2 * 8 * BATCH * 4096 * sizeof(float);
  float* invLg;
  float* invUg;
  if (ws_size >= inv_need) {
    invLg = (float*)((char*)d_ws + small_end);
    invUg = invLg + (size_t)8 * BATCH * 4096;
  } else {
    invLg = out1;
    invUg = out1 + (size_t)8 * BATCH * 4096;
  }

  k_convert<<<BATCH, 256, 0, stream>>>(mask_raw, tgt_raw, cmask, ctgt);
  k_build_M<<<dim3(MS, BATCH), 256, 0, stream>>>(scores, cmask, Mbuf);

  for (int kb = 0; kb < MS; kb += PB) {
    k_panel64<<<BATCH, 256, 0, stream>>>(Mbuf, kb, ld2, invLg, invUg);
    int rem2 = MS - kb - PB;
    if (rem2 > 0) {
      int nt = (rem2 + 63) / 64;
      k_trsm<<<dim3(nt, 2, BATCH), 256, 0, stream>>>(Mbuf, kb, invLg, invUg);
      k_update<<<dim3(nt, nt, BATCH), 256, 0, stream>>>(Mbuf, kb);
    }
  }

  k_solve<<<dim3(BATCH, 16), 256, 0, stream>>>(Mbuf, scores, cmask, out1);
  k_gold<<<BATCH, 256, 0, stream>>>(scores, cmask, ctgt, goldb, cntb);
  k_final<<<1, 1, 0, stream>>>(ld2, goldb, cntb, out);
}

// Round 5
// 1745.474 us; speedup vs baseline: 24.1737x; 1.1078x over previous
//
#include <hip/hip_runtime.h>
#include <math.h>

#define BATCH 64
#define NN 512
#define MS 511                       // minor size (root row/col removed)
#define LDM 512                      // row stride
#define MSTRIDE ((size_t)MS*LDM)     // floats per batch in ws M buffer
#define OSTRIDE ((size_t)NN*NN)
#define PB 64                        // LU panel width
#define YTS 513                      // Yt col stride (rotation banking)

// ---- input layout conversion ----
__global__ void k_convert(const void* __restrict__ mask_raw,
                          const void* __restrict__ tgt_raw,
                          int* __restrict__ cmask, int* __restrict__ ctgt) {
  int b = blockIdx.x;
  const unsigned char* mb = (const unsigned char*)mask_raw;
  const int* mw = (const int*)mask_raw;
  const int* tw = (const int*)tgt_raw;
  bool m_bytes = (mb[1] | mb[2] | mb[3]) != 0;
  bool m_64 = false;
  if (!m_bytes) {
    int acc = 0;
    for (int j = 1; j < 32; j += 2) acc |= mw[j];
    m_64 = (acc == 0);
  }
  int tacc = 0;
  for (int j = 1; j < 32; j += 2) tacc |= tw[j];
  bool t_64 = (tacc == 0);
  for (int i = threadIdx.x; i < NN; i += blockDim.x) {
    size_t idx = (size_t)b * NN + i;
    int mv;
    if (m_bytes) mv = mb[idx] != 0;
    else if (m_64) mv = mw[2 * idx] != 0;
    else mv = mw[idx] != 0;
    cmask[idx] = mv;
    ctgt[idx] = t_64 ? tw[2 * idx] : tw[idx];
  }
}

// ---- build Laplacian minor M[b], single pass over scores ----
__global__ void k_build_M(const float* __restrict__ scores,
                          const int* __restrict__ mask,
                          float* __restrict__ M) {
  int b = blockIdx.y;
  int ip = blockIdx.x;
  int i = ip + 1;
  const int* mrow = mask + (size_t)b * NN;
  float* Mrow = M + (size_t)b * MSTRIDE + (size_t)ip * LDM;
  int tid = threadIdx.x;
  if (!mrow[i]) {
    for (int jp = tid; jp < MS; jp += 256)
      Mrow[jp] = (jp == ip) ? 1.0f : 0.0f;
    return;
  }
  const float* srow = scores + ((size_t)b * NN + i) * NN;
  double part = 0.0;
  for (int j = tid; j < NN; j += 256) {
    bool mj = (j == 0) || (mrow[j] != 0);
    float e = mj ? expf(srow[j]) : 0.0f;
    part += (double)e;
    if (j >= 1) Mrow[j - 1] = -e;
  }
  __shared__ double red[256];
  red[tid] = part;
  __syncthreads();
  for (int s = 128; s > 0; s >>= 1) {
    if (tid < s) red[tid] += red[tid + s];
    __syncthreads();
  }
  if (tid == (i & 255)) Mrow[ip] += (float)red[0];
}

// ---- factor 64x64 diagonal block + invert L11/U11 ----
__global__ __launch_bounds__(256) void k_panel64(float* __restrict__ M, int kb,
                                                 double* __restrict__ ld2,
                                                 float* __restrict__ invLg,
                                                 float* __restrict__ invUg) {
  int b = blockIdx.x;
  float* Mb = M + (size_t)b * MSTRIDE;
  int tid = threadIdx.x;
  __shared__ float A[64 * 65];
  __shared__ float XU[64 * 66];
  __shared__ float XL[64 * 66];
  __shared__ double lg[64];

  for (int idx = tid; idx < 64 * 64; idx += 256) {
    int r = idx >> 6, c = idx & 63;
    int gr = kb + r, gc = kb + c;
    A[r * 65 + c] = (gr < MS && gc < MS) ? Mb[(size_t)gr * LDM + gc]
                                         : ((r == c) ? 1.0f : 0.0f);
  }
  __syncthreads();

  int rr = tid >> 2, sub = tid & 3;
  for (int j = 0; j < 63; ++j) {
    if (rr > j) {
      float piv = A[j * 65 + j];
      float l = A[rr * 65 + j] / piv;
      if (sub == 0) A[rr * 65 + j] = l;
      for (int c = j + 1 + sub; c < 64; c += 4)
        A[rr * 65 + c] -= l * A[j * 65 + c];
    }
    __syncthreads();
  }
  if (tid < 64) lg[tid] = log(fabs((double)A[tid * 65 + tid]));
  for (int idx = tid; idx < 64 * 64; idx += 256) {
    int r = idx >> 6, c = idx & 63;
    int gr = kb + r, gc = kb + c;
    if (gr < MS && gc < MS) Mb[(size_t)gr * LDM + gc] = A[r * 65 + c];
  }
  __syncthreads();
  if (tid == 0) {
    double a = 0.0;
    for (int j = 0; j < 64; ++j) a += lg[j];
    ld2[(kb >> 6) * BATCH + b] = a;
  }

  {
    int c = rr;
    if (sub == 0) XU[c * 66 + c] = 1.0f / A[c * 65 + c];
    for (int r2 = c - 1; r2 >= 0; --r2) {
      float s = 0.0f;
      for (int k = r2 + 1 + sub; k <= c; k += 4)
        s += A[r2 * 65 + k] * XU[c * 66 + k];
      s += __shfl_xor(s, 1, 4);
      s += __shfl_xor(s, 2, 4);
      if (sub == 0) XU[c * 66 + r2] = -s / A[r2 * 65 + r2];
    }
  }
  {
    int c = rr;
    if (sub == 0) XL[c * 66 + c] = 1.0f;
    for (int r2 = c + 1; r2 < 64; ++r2) {
      float s = 0.0f;
      for (int k = c + sub; k < r2; k += 4)
        s += A[r2 * 65 + k] * XL[c * 66 + k];
      s += __shfl_xor(s, 1, 4);
      s += __shfl_xor(s, 2, 4);
      if (sub == 0) XL[c * 66 + r2] = -s;
    }
  }
  __syncthreads();
  float* iLg = invLg + ((size_t)(kb >> 6) * BATCH + b) * 4096;
  float* iUg = invUg + ((size_t)(kb >> 6) * BATCH + b) * 4096;
  for (int idx = tid; idx < 4096; idx += 256) {
    int r = idx >> 6, c = idx & 63;
    iUg[idx] = (r <= c) ? XU[c * 66 + r] : 0.0f;
    iLg[idx] = (r >= c) ? XL[c * 66 + r] : 0.0f;
  }
}

// ---- TRSM-as-GEMM: side0: U12 = invL11 * A12 ; side1: L21 = A21 * invU11 ----
__global__ __launch_bounds__(256) void k_trsm(float* __restrict__ M, int kb,
                                              const float* __restrict__ invLg,
                                              const float* __restrict__ invUg) {
  int b = blockIdx.z;
  int t = blockIdx.x;
  int side = blockIdx.y;
  float* Mb = M + (size_t)b * MSTRIDE;
  const float* inv = (side == 0 ? invLg : invUg) + ((size_t)(kb >> 6) * BATCH + b) * 4096;
  __shared__ float Fs[64 * 65];
  __shared__ float As[64 * 65];
  int tid = threadIdx.x;
  int off = kb + 64 + t * 64;
  for (int idx = tid; idx < 4096; idx += 256)
    Fs[(idx >> 6) * 65 + (idx & 63)] = inv[idx];
  for (int idx = tid; idx < 4096; idx += 256) {
    int r = idx >> 6, c = idx & 63;
    int gr, gc;
    if (side == 0) { gr = kb + r; gc = off + c; }
    else           { gr = off + r; gc = kb + c; }
    As[r * 65 + c] = (gr < MS && gc < MS) ? Mb[(size_t)gr * LDM + gc] : 0.0f;
  }
  __syncthreads();
  int tx = tid & 15, ty = tid >> 4;
  float acc[4][4];
#pragma unroll
  for (int i = 0; i < 4; ++i)
#pragma unroll
    for (int j = 0; j < 4; ++j) acc[i][j] = 0.0f;
  if (side == 0) {
#pragma unroll 4
    for (int k = 0; k < 64; ++k) {
      float av[4], bv[4];
#pragma unroll
      for (int i = 0; i < 4; ++i) av[i] = Fs[(ty * 4 + i) * 65 + k];
#pragma unroll
      for (int j = 0; j < 4; ++j) bv[j] = As[k * 65 + tx * 4 + j];
#pragma unroll
      for (int i = 0; i < 4; ++i)
#pragma unroll
        for (int j = 0; j < 4; ++j) acc[i][j] = fmaf(av[i], bv[j], acc[i][j]);
    }
  } else {
#pragma unroll 4
    for (int k = 0; k < 64; ++k) {
      float av[4], bv[4];
#pragma unroll
      for (int i = 0; i < 4; ++i) av[i] = As[(ty * 4 + i) * 65 + k];
#pragma unroll
      for (int j = 0; j < 4; ++j) bv[j] = Fs[k * 65 + tx * 4 + j];
#pragma unroll
      for (int i = 0; i < 4; ++i)
#pragma unroll
        for (int j = 0; j < 4; ++j) acc[i][j] = fmaf(av[i], bv[j], acc[i][j]);
    }
  }
#pragma unroll
  for (int i = 0; i < 4; ++i) {
#pragma unroll
    for (int j = 0; j < 4; ++j) {
      int gr, gc;
      if (side == 0) { gr = kb + ty * 4 + i; gc = off + tx * 4 + j; }
      else           { gr = off + ty * 4 + i; gc = kb + tx * 4 + j; }
      if (gr < MS && gc < MS) Mb[(size_t)gr * LDM + gc] = acc[i][j];
    }
  }
}

// ---- trailing rank-64 update: C -= L21 * U12, 128x128 tiles, 8x8 regs ----
__global__ __launch_bounds__(256) void k_update(float* __restrict__ M, int kb) {
  int b = blockIdx.z;
  float* Mb = M + (size_t)b * MSTRIDE;
  int row0 = kb + PB + blockIdx.x * 128;
  int col0 = kb + PB + blockIdx.y * 128;
  __shared__ __align__(16) float As[128 * 68];
  __shared__ __align__(16) float Bs[64 * 132];
  int tid = threadIdx.x;
  // A: rows row0..row0+127, cols kb..kb+63
  for (int idx = tid; idx < 2048; idx += 256) {
    int r = idx >> 4, q = (idx & 15) * 4;
    int gr = row0 + r;
    float4 v = make_float4(0.f, 0.f, 0.f, 0.f);
    if (gr < MS) v = *(const float4*)&Mb[(size_t)gr * LDM + kb + q];
    *(float4*)&As[r * 68 + q] = v;
  }
  // B: rows kb..kb+63, cols col0..col0+127
  for (int idx = tid; idx < 2048; idx += 256) {
    int r = idx >> 5, q = (idx & 31) * 4;
    int gc = col0 + q;
    float4 v;
    const float* src = &Mb[(size_t)(kb + r) * LDM];
    if (gc + 3 < MS) v = *(const float4*)&src[gc];
    else {
      v.x = (gc < MS) ? src[gc] : 0.f;
      v.y = (gc + 1 < MS) ? src[gc + 1] : 0.f;
      v.z = (gc + 2 < MS) ? src[gc + 2] : 0.f;
      v.w = (gc + 3 < MS) ? src[gc + 3] : 0.f;
    }
    *(float4*)&Bs[r * 132 + q] = v;
  }
  __syncthreads();
  int tx = tid & 15, ty = tid >> 4;
  float acc[8][8];
#pragma unroll
  for (int i = 0; i < 8; ++i) {
    int gr = row0 + ty + 16 * i;
#pragma unroll
    for (int j = 0; j < 8; ++j) {
      int gc = col0 + tx + 16 * j;
      acc[i][j] = (gr < MS && gc < MS) ? Mb[(size_t)gr * LDM + gc] : 0.0f;
    }
  }
#pragma unroll 2
  for (int k = 0; k < 64; ++k) {
    float av[8], bv[8];
#pragma unroll
    for (int i = 0; i < 8; ++i) av[i] = As[(ty + 16 * i) * 68 + k];
#pragma unroll
    for (int j = 0; j < 8; ++j) bv[j] = Bs[k * 132 + tx + 16 * j];
#pragma unroll
    for (int i = 0; i < 8; ++i)
#pragma unroll
      for (int j = 0; j < 8; ++j)
        acc[i][j] = fmaf(-av[i], bv[j], acc[i][j]);
  }
#pragma unroll
  for (int i = 0; i < 8; ++i) {
    int gr = row0 + ty + 16 * i;
    if (gr < MS) {
#pragma unroll
      for (int j = 0; j < 8; ++j) {
        int gc = col0 + tx + 16 * j;
        if (gc < MS) Mb[(size_t)gr * LDM + gc] = acc[i][j];
      }
    }
  }
}

// ---- all-GEMM inverse columns (32/WG) using stored invL/invU + fused marginals ----
__global__ __launch_bounds__(256) void k_solve(const float* __restrict__ M,
                                               const float* __restrict__ invLg,
                                               const float* __restrict__ invUg,
                                               const float* __restrict__ scores,
                                               const int* __restrict__ mask,
                                               float* __restrict__ out1,
                                               int b0) {
  int b = b0 + blockIdx.x;
  int cb = blockIdx.y;
  const float* Mb = M + (size_t)b * MSTRIDE;
  int tid = threadIdx.x;
  int c0 = cb * 32;
  int fb = c0 & ~63;
  __shared__ float Yt[32 * YTS];     // 65.7 KB, Yt[c][r]
  __shared__ float S[64 * 33];       // 8.4 KB staging
  int tx = tid & 7, ty = tid >> 3;   // tx: col-group (4 cols: tx+8j), ty: 0..31

  for (int idx = tid; idx < 32 * YTS; idx += 256) Yt[idx] = 0.0f;
  __syncthreads();
  {  // init rows fb..fb+63 = invL_fb columns (c0-fb)+c  (= forward solve of identity block)
    const float* iL = invLg + ((size_t)(fb >> 6) * BATCH + b) * 4096;
    int coff = c0 - fb;
    for (int idx = tid; idx < 2048; idx += 256) {
      int r2 = idx >> 5, c = idx & 31;
      Yt[c * YTS + fb + r2] = iL[r2 * 64 + coff + c];
    }
  }
  __syncthreads();

  // ======== forward: L Y = I ========
  for (int jb = fb; jb < MS; jb += 64) {
    if (jb > fb) {  // diag: Y[jb] = invL_jb * Y[jb]
      const float* iL = invLg + ((size_t)(jb >> 6) * BATCH + b) * 4096;
      float acc[2][4] = {{0.f,0.f,0.f,0.f},{0.f,0.f,0.f,0.f}};
      for (int kh = 0; kh < 64; kh += 32) {
        for (int idx = tid; idx < 2048; idx += 256) {
          int rl = idx >> 5, kk = idx & 31;
          S[rl * 33 + kk] = iL[rl * 64 + kh + kk];
        }
        __syncthreads();
#pragma unroll 4
        for (int kk = 0; kk < 32; ++kk) {
          int yr = jb + kh + kk;
          float bv[4];
#pragma unroll
          for (int j = 0; j < 4; ++j) bv[j] = Yt[(tx + 8 * j) * YTS + yr];
          float a0 = S[ty * 33 + kk];
          float a1 = S[(ty + 32) * 33 + kk];
#pragma unroll
          for (int j = 0; j < 4; ++j) {
            acc[0][j] = fmaf(a0, bv[j], acc[0][j]);
            acc[1][j] = fmaf(a1, bv[j], acc[1][j]);
          }
        }
        __syncthreads();
      }
#pragma unroll
      for (int j = 0; j < 4; ++j) {
        Yt[(tx + 8 * j) * YTS + jb + ty] = acc[0][j];
        Yt[(tx + 8 * j) * YTS + jb + ty + 32] = acc[1][j];
      }
      __syncthreads();
    }
    for (int R0 = jb + 64; R0 < MS; R0 += 64) {  // below: Y[R0] -= L[R0,jb]*Y[jb]
      int r0 = R0 + ty, r1 = R0 + ty + 32;
      float acc[2][4];
#pragma unroll
      for (int j = 0; j < 4; ++j) {
        acc[0][j] = Yt[(tx + 8 * j) * YTS + r0];
        acc[1][j] = Yt[(tx + 8 * j) * YTS + r1];
      }
      for (int kh = 0; kh < 64; kh += 32) {
        for (int idx = tid; idx < 2048; idx += 256) {
          int rl = idx >> 5, kk = idx & 31;
          int gr = R0 + rl;
          S[rl * 33 + kk] = (gr < MS) ? Mb[(size_t)gr * LDM + jb + kh + kk] : 0.0f;
        }
        __syncthreads();
#pragma unroll 4
        for (int kk = 0; kk < 32; ++kk) {
          int yr = jb + kh + kk;
          float bv[4];
#pragma unroll
          for (int j = 0; j < 4; ++j) bv[j] = Yt[(tx + 8 * j) * YTS + yr];
          float a0 = S[ty * 33 + kk];
          float a1 = S[(ty + 32) * 33 + kk];
#pragma unroll
          for (int j = 0; j < 4; ++j) {
            acc[0][j] = fmaf(-a0, bv[j], acc[0][j]);
            acc[1][j] = fmaf(-a1, bv[j], acc[1][j]);
          }
        }
        __syncthreads();
      }
      if (r0 < MS) {
#pragma unroll
        for (int j = 0; j < 4; ++j) Yt[(tx + 8 * j) * YTS + r0] = acc[0][j];
      }
      if (r1 < MS) {
#pragma unroll
        for (int j = 0; j < 4; ++j) Yt[(tx + 8 * j) * YTS + r1] = acc[1][j];
      }
    }
  }
  __syncthreads();

  // ======== backward: U X = Y ========
  for (int jb = 448; jb >= 0; jb -= 64) {
    {  // diag: X[jb] = invU_jb * Y[jb]
      const float* iU = invUg + ((size_t)(jb >> 6) * BATCH + b) * 4096;
      float acc[2][4] = {{0.f,0.f,0.f,0.f},{0.f,0.f,0.f,0.f}};
      for (int kh = 0; kh < 64; kh += 32) {
        for (int idx = tid; idx < 2048; idx += 256) {
          int rl = idx >> 5, kk = idx & 31;
          S[rl * 33 + kk] = iU[rl * 64 + kh + kk];
        }
        __syncthreads();
#pragma unroll 4
        for (int kk = 0; kk < 32; ++kk) {
          int yr = jb + kh + kk;
          float bv[4];
#pragma unroll
          for (int j = 0; j < 4; ++j) bv[j] = Yt[(tx + 8 * j) * YTS + yr];
          float a0 = S[ty * 33 + kk];
          float a1 = S[(ty + 32) * 33 + kk];
#pragma unroll
          for (int j = 0; j < 4; ++j) {
            acc[0][j] = fmaf(a0, bv[j], acc[0][j]);
            acc[1][j] = fmaf(a1, bv[j], acc[1][j]);
          }
        }
        __syncthreads();
      }
#pragma unroll
      for (int j = 0; j < 4; ++j) {
        Yt[(tx + 8 * j) * YTS + jb + ty] = acc[0][j];
        Yt[(tx + 8 * j) * YTS + jb + ty + 32] = acc[1][j];
      }
      __syncthreads();
    }
    for (int R0 = 0; R0 < jb; R0 += 64) {  // above: Y[R0] -= U[R0,jb]*X[jb]
      int r0 = R0 + ty, r1 = R0 + ty + 32;
      float acc[2][4];
#pragma unroll
      for (int j = 0; j < 4; ++j) {
        acc[0][j] = Yt[(tx + 8 * j) * YTS + r0];
        acc[1][j] = Yt[(tx + 8 * j) * YTS + r1];
      }
      for (int kh = 0; kh < 64; kh += 32) {
        for (int idx = tid; idx < 2048; idx += 256) {
          int rl = idx >> 5, kk = idx & 31;
          int gc = jb + kh + kk;
          S[rl * 33 + kk] = (gc < MS) ? Mb[(size_t)(R0 + rl) * LDM + gc] : 0.0f;
        }
        __syncthreads();
#pragma unroll 4
        for (int kk = 0; kk < 32; ++kk) {
          int yr = jb + kh + kk;
          float bv[4];
#pragma unroll
          for (int j = 0; j < 4; ++j) bv[j] = Yt[(tx + 8 * j) * YTS + yr];
          float a0 = S[ty * 33 + kk];
          float a1 = S[(ty + 32) * 33 + kk];
#pragma unroll
          for (int j = 0; j < 4; ++j) {
            acc[0][j] = fmaf(-a0, bv[j], acc[0][j]);
            acc[1][j] = fmaf(-a1, bv[j], acc[1][j]);
          }
        }
        __syncthreads();
      }
#pragma unroll
      for (int j = 0; j < 4; ++j) {
        Yt[(tx + 8 * j) * YTS + r0] = acc[0][j];
        Yt[(tx + 8 * j) * YTS + r1] = acc[1][j];
      }
    }
  }
  __syncthreads();

  // ======== fused marginals: out row i = cg+1 from K column cg ========
  const int* mrow = mask + (size_t)b * NN;
  const float* sb = scores + (size_t)b * NN * NN;
  float* ob = out1 + (size_t)b * OSTRIDE;
  for (int c = 0; c < 32; ++c) {
    int cg = c0 + c;
    if (cg >= MS) break;             // pad column
    int i = cg + 1;
    float* orow = ob + (size_t)i * NN;
    if (mrow[i] == 0) {
      orow[tid] = 0.0f;
      orow[tid + 256] = 0.0f;
    } else {
      const float* srow = sb + (size_t)i * NN;
      float kd = Yt[c * YTS + cg];
#pragma unroll
      for (int h = 0; h < 2; ++h) {
        int k = tid + h * 256;
        bool mk = (k == 0) || (mrow[k] != 0);
        float v = 0.0f;
        if (mk) {
          float s2 = (k >= 1) ? Yt[c * YTS + (k - 1)] : 0.0f;
          v = expf(srow[k]) * (kd - s2);
        }
        orow[k] = v;
      }
    }
  }
  if (cb == 0) {
    ob[tid] = 0.0f;
    ob[tid + 256] = 0.0f;
  }
}

// ---- gold score + mask count per batch ----
__global__ void k_gold(const float* __restrict__ scores,
                       const int* __restrict__ mask,
                       const int* __restrict__ target,
                       double* __restrict__ goldb, int* __restrict__ cntb) {
  int b = blockIdx.x;
  const int* mrow = mask + (size_t)b * NN;
  const int* trow = target + (size_t)b * NN;
  double g = 0.0;
  int c = 0;
  for (int i = threadIdx.x; i < NN; i += blockDim.x) {
    if (mrow[i] != 0) {
      g += (double)scores[((size_t)b * NN + i) * NN + trow[i]];
      c++;
    }
  }
  __shared__ double gs[256];
  __shared__ int cs[256];
  gs[threadIdx.x] = g;
  cs[threadIdx.x] = c;
  __syncthreads();
  for (int s = 128; s > 0; s >>= 1) {
    if (threadIdx.x < s) {
      gs[threadIdx.x] += gs[threadIdx.x + s];
      cs[threadIdx.x] += cs[threadIdx.x + s];
    }
    __syncthreads();
  }
  if (threadIdx.x == 0) { goldb[b] = gs[0]; cntb[b] = cs[0]; }
}

__global__ void k_final(const double* __restrict__ ld2,
                        const double* __restrict__ goldb,
                        const int* __restrict__ cntb, float* __restrict__ out) {
  double lz = 0.0, g = 0.0;
  long long cnt = 0;
  for (int s = 0; s < 8 * BATCH; ++s) lz += ld2[s];
  for (int b = 0; b < BATCH; ++b) { g += goldb[b]; cnt += cntb[b]; }
  out[0] = (float)((lz - g) / (double)cnt);
}

extern "C" void kernel_launch(void* const* d_in, const int* in_sizes, int n_in,
                              void* d_out, int out_size, void* d_ws, size_t ws_size,
                              hipStream_t stream) {
  const float* scores = (const float*)d_in[0];
  const void* mask_raw = d_in[1];
  const void* tgt_raw = d_in[2];
  float* out = (float*)d_out;
  float* out1 = out + 1;

  float* Mbuf = (float*)d_ws;
  size_t moff = (MSTRIDE * BATCH * sizeof(float) + 255) & ~(size_t)255;
  double* ld2 = (double*)((char*)d_ws + moff);
  double* goldb = ld2 + 8 * BATCH;
  int* cntb = (int*)(goldb + BATCH);
  int* cmask = cntb + BATCH;
  int* ctgt = cmask + BATCH * NN;

  const size_t INVFLOATS = (size_t)8 * BATCH * 4096;    // per L or U set
  size_t small_end = moff + 512 * 1024;
  size_t inv_need = small_end + 2 * INVFLOATS * sizeof(float);
  bool inv_in_ws = (ws_size >= inv_need);
  float* invLg;
  float* invUg;
  if (inv_in_ws) {
    invLg = (float*)((char*)d_ws + small_end);
    invUg = invLg + INVFLOATS;
  } else {
    // stash in tail of d_out (batches 47..63 marginal area, 17.8 MB >= 16.8 MB)
    invLg = out1 + (size_t)47 * OSTRIDE;
    invUg = invLg + INVFLOATS;
  }

  k_convert<<<BATCH, 256, 0, stream>>>(mask_raw, tgt_raw, cmask, ctgt);
  k_build_M<<<dim3(MS, BATCH), 256, 0, stream>>>(scores, cmask, Mbuf);

  for (int kb = 0; kb < MS; kb += PB) {
    k_panel64<<<BATCH, 256, 0, stream>>>(Mbuf, kb, ld2, invLg, invUg);
    int rem2 = MS - kb - PB;
    if (rem2 > 0) {
      int nt64 = (rem2 + 63) / 64;
      k_trsm<<<dim3(nt64, 2, BATCH), 256, 0, stream>>>(Mbuf, kb, invLg, invUg);
      int nt128 = (rem2 + 127) / 128;
      k_update<<<dim3(nt128, nt128, BATCH), 256, 0, stream>>>(Mbuf, kb);
    }
  }

  if (inv_in_ws) {
    k_solve<<<dim3(BATCH, 16), 256, 0, stream>>>(Mbuf, invLg, invUg, scores, cmask, out1, 0);
  } else {
    // phase 1: batches 0..46 (marginal writes disjoint from inv stash)
    k_solve<<<dim3(47, 16), 256, 0, stream>>>(Mbuf, invLg, invUg, scores, cmask, out1, 0);
    // relocate inv into retired Mbuf rows (batches 0..16 no longer needed)
    hipMemcpyAsync(Mbuf, invLg, 2 * INVFLOATS * sizeof(float),
                   hipMemcpyDeviceToDevice, stream);
    float* invL2 = Mbuf;
    float* invU2 = Mbuf + INVFLOATS;
    // phase 2: batches 47..63
    k_solve<<<dim3(17, 16), 256, 0, stream>>>(Mbuf, invL2, invU2, scores, cmask, out1, 47);
  }

  k_gold<<<BATCH, 256, 0, stream>>>(scores, cmask, ctgt, goldb, cntb);
  k_final<<<1, 1, 0, stream>>>(ld2, goldb, cntb, out);
}